// Round 15
// baseline (135.883 us; speedup 1.0000x reference)
//
#include <hip/hip_runtime.h>
#include <stdint.h>

#define NN 16384
#define MM 16384
#define DD 8
#define DV 16
#define WAVES 4
#define MT 2                        // 16-row m-tiles per wave
#define ROWS_WAVE (MT * 16)         // 32
#define ROWS_BLK (WAVES * ROWS_WAVE)// 128
#define JSPLIT 32
#define JCHUNK (MM / JSPLIT)        // 512
#define J32 (JCHUNK / 32)           // 16 iterations per block

typedef short bf8 __attribute__((ext_vector_type(8)));   // 8 bf16 (4 VGPR)
typedef short s2v __attribute__((ext_vector_type(2)));   // 2 bf16, one b32 store
typedef float f32x4 __attribute__((ext_vector_type(4))); // MFMA C/D

#define C3SQ 10.406844905028037f     /* 5*log2(e)^2 : folded into tables */
#define C2S  (1.2909944487358056f / 10.406844905028037f)  /* c2/c3sq */
#define LN2  0.6931471805599453f

__device__ __forceinline__ unsigned short f2bf(float f) {
    union { float f; uint32_t u; } c; c.f = f;
    uint32_t u = c.u + 0x7FFF + ((c.u >> 16) & 1);       // RNE
    return (unsigned short)(u >> 16);
}
__device__ __forceinline__ float bf2f(unsigned short h) {
    union { float f; uint32_t u; } c; c.u = ((uint32_t)h) << 16;
    return c.f;
}

#define BF16_ONE ((short)0x3F80)

// R15 prep: one WAVE per table tile -> 1536 waves (6 waves/CU), 6x the
// latency-hiding of R12's shape (the scattered b-gather ran at 2 waves/CU:
// suspected source of the constant ~45us total-main gap).
//   waves    0..1023: ytbl[tile16]  (scaled d2 fold, R14-proven)
//   waves 1024..1535: btbl[tile32]  (PERMUTED K-order, R14-proven)
//   blocks 0..255 also zero d_out (1 MB).
__global__ __launch_bounds__(256) void prep_frags(const float* __restrict__ ls,
                                                  const float* __restrict__ y,
                                                  const float* __restrict__ b,
                                                  bf8* __restrict__ ytbl,
                                                  bf8* __restrict__ btbl,
                                                  float4* __restrict__ outz) {
    const int w = blockIdx.x * 4 + (threadIdx.x >> 6);    // global wave id
    const int lane = threadIdx.x & 63;
    const int n = lane & 15, quad = lane >> 4;

    if (blockIdx.x < 256)
        outz[blockIdx.x * 256 + threadIdx.x] = make_float4(0.f, 0.f, 0.f, 0.f);

    float lsv[DD];
#pragma unroll
    for (int d = 0; d < DD; ++d) lsv[d] = ls[d];

    if (w < 1024) {                   // ---- ytbl tile16 = w ----
        const int tile = w;
        const float4* yr4 = (const float4*)(y + (size_t)(tile * 16 + n) * DD);
        float4 ya = yr4[0], yb = yr4[1];
        float yv[DD] = {ya.x, ya.y, ya.z, ya.w, yb.x, yb.y, yb.z, yb.w};

        float syv = 0.f;
        unsigned short wh[DD], wl[DD];
#pragma unroll
        for (int d = 0; d < DD; ++d) {
            syv = fmaf(lsv[d] * yv[d], yv[d], syv);
            float wv = -2.f * C3SQ * yv[d];     // scale in fp32, THEN split
            wh[d] = f2bf(wv);
            wl[d] = f2bf(wv - bf2f(wh[d]));
        }

        bf8 fr;
        if (quad < 3) {
#pragma unroll
            for (int d = 0; d < DD; ++d)
                fr[d] = (short)((quad == 2) ? wl[d] : wh[d]);
        } else {
            float csy = C3SQ * syv;
            unsigned short sh = f2bf(csy);
            unsigned short sl = f2bf(csy - bf2f(sh));
            fr[0] = (short)sh;      // k=24: 1 * csy_hi
            fr[1] = (short)sl;      // k=25: 1 * csy_lo
            fr[2] = BF16_ONE;       // k=26: csx_hi * 1
            fr[3] = BF16_ONE;       // k=27: csx_lo * 1
            fr[4] = 0; fr[5] = 0; fr[6] = 0; fr[7] = 0;
        }
        ytbl[tile * 64 + lane] = fr;
    } else {                          // ---- btbl tile32 = w - 1024 ----
        const int tile = w - 1024;    // 0..511
        bf8 bfr;
#pragma unroll
        for (int s = 0; s < 8; ++s) {
            int k = quad * 8 + s;
            int jl = (k >> 1) + ((k & 1) << 4);   // interleaved klds col -> j
            float bv = b[(size_t)(tile * 32 + jl) * DV + n];
            bfr[s] = (short)f2bf(bv);
        }
        btbl[tile * 64 + lane] = bfr;
    }
}

// R14 structure (proven PASS, 135us) + register prefetch of next-iter
// tables, rotated in AFTER phase B consumes bb (R8's rotation structure,
// asm-free — the R6-R8 failures are pinned on the inline-asm pk ops, the
// only element present in all three failures and absent from all passes).
__global__ __launch_bounds__(256, 8) void matern_mfma(const float* __restrict__ ls,
                                                      const float* __restrict__ x,
                                                      const bf8* __restrict__ ytbl,
                                                      const bf8* __restrict__ btbl,
                                                      float* __restrict__ out) {
    const int t = threadIdx.x;
    const int lane = t & 63, wave = t >> 6;
    const int n = lane & 15, quad = lane >> 4;
    const int waverow = blockIdx.x * ROWS_BLK + wave * ROWS_WAVE;

    // [wave][mt][m][40]: 80B rows; b32 writes 2-way free; b128 reads 2-way
    // free-ish (the constant 2^21 SQ_LDS_BANK_CONFLICT = 4cyc/read floor).
    __shared__ __attribute__((aligned(16))) unsigned short klds[WAVES][MT][16][40];

    float lsv[DD];
#pragma unroll
    for (int d = 0; d < DD; ++d) lsv[d] = ls[d];

    // A-frags: quad 0/2 -> xls_hi, quad 1 -> xls_lo, quad 3 -> {1,1,csx_hi,csx_lo}
    bf8 afrag[MT];
#pragma unroll
    for (int mt = 0; mt < MT; ++mt) {
        const float* xr = x + (size_t)(waverow + mt * 16 + n) * DD;
        float sx = 0.f;
        unsigned short xh[DD], xl[DD];
#pragma unroll
        for (int d = 0; d < DD; ++d) {
            float xv = xr[d];
            float xlsv = lsv[d] * xv;
            sx = fmaf(xlsv, xv, sx);
            xh[d] = f2bf(xlsv);
            xl[d] = f2bf(xlsv - bf2f(xh[d]));
        }
        bf8 fr;
        if (quad == 3) {
            float csx = C3SQ * sx;               // scale in fp32, THEN split
            unsigned short sh = f2bf(csx);
            unsigned short sl = f2bf(csx - bf2f(sh));
            fr[0] = BF16_ONE;   // k=24: 1 * csy_hi
            fr[1] = BF16_ONE;   // k=25: 1 * csy_lo
            fr[2] = (short)sh;  // k=26: csx_hi * 1
            fr[3] = (short)sl;  // k=27: csx_lo * 1
            fr[4] = 0; fr[5] = 0; fr[6] = 0; fr[7] = 0;
        } else {
#pragma unroll
            for (int d = 0; d < DD; ++d)
                fr[d] = (short)((quad == 1) ? xl[d] : xh[d]);
        }
        afrag[mt] = fr;
    }

    f32x4 acc[MT];
#pragma unroll
    for (int mt = 0; mt < MT; ++mt) acc[mt] = (f32x4){0.f, 0.f, 0.f, 0.f};

    const int tile16base = blockIdx.y * (JCHUNK / 16);
    const int tile32base = blockIdx.y * (JCHUNK / 32);

    // Live tables for iter 0
    bf8 yA = ytbl[(size_t)tile16base * 64 + lane];
    bf8 yB = ytbl[(size_t)(tile16base + 1) * 64 + lane];
    bf8 bb = btbl[(size_t)tile32base * 64 + lane];

#pragma unroll 1
    for (int it = 0; it < J32; ++it) {
#pragma unroll
        for (int mt = 0; mt < MT; ++mt) {
            f32x4 z = (f32x4){0.f, 0.f, 0.f, 0.f};
            f32x4 s0 = __builtin_amdgcn_mfma_f32_16x16x32_bf16(afrag[mt], yA, z, 0, 0, 0);
            f32x4 s1 = __builtin_amdgcn_mfma_f32_16x16x32_bf16(afrag[mt], yB, z, 0, 0, 0);
#pragma unroll
            for (int s = 0; s < 4; ++s) {
                // s0/s1 ARE c3sq*d2; |.| eats rounding-noise negatives (free mod)
                float a0 = __builtin_fabsf(s0[s]);
                float a1 = __builtin_fabsf(s1[s]);
                float t0 = __builtin_amdgcn_sqrtf(a0);          // = |c3|*r
                float t1 = __builtin_amdgcn_sqrtf(a1);
                float e0 = __builtin_amdgcn_exp2f(-t0);         // neg = free mod
                float e1 = __builtin_amdgcn_exp2f(-t1);
                float k0 = fmaf(C2S, a0, fmaf(LN2, t0, 1.f)) * e0;
                float k1 = fmaf(C2S, a1, fmaf(LN2, t1, 1.f)) * e1;
                s2v w;
#if __has_builtin(__builtin_amdgcn_cvt_pk_bf16_f32)
                typedef __bf16 bf2v __attribute__((ext_vector_type(2)));
                bf2v pk = __builtin_amdgcn_cvt_pk_bf16_f32(k0, k1);
                union { bf2v v; s2v s; } cv; cv.v = pk;
                w = cv.s;
#else
                w[0] = (short)((__float_as_uint(k0) + 0x8000u) >> 16);
                w[1] = (short)((__float_as_uint(k1) + 0x8000u) >> 16);
#endif
                // one b32 store: cols 2n (tile0) / 2n+1 (tile1), interleaved
                *(s2v*)&klds[wave][mt][quad * 4 + s][2 * n] = w;
            }
        }

        // Prefetch next iter into SEPARATE regs (bb stays live for phase B;
        // rotation strictly after phase B below).
        bf8 yAn, yBn, bbn;
        if (it + 1 < J32) {
            const int tl = tile16base + (it + 1) * 2;
            yAn = ytbl[(size_t)tl * 64 + lane];
            yBn = ytbl[(size_t)(tl + 1) * 64 + lane];
            bbn = btbl[(size_t)(tile32base + it + 1) * 64 + lane];
        }

        // Phase B: C/D->A via wave-private LDS (interleaved cols = btbl K-order)
#pragma unroll
        for (int mt = 0; mt < MT; ++mt) {
            const bf8* kp = (const bf8*)&klds[wave][mt][n][quad * 8];
            acc[mt] = __builtin_amdgcn_mfma_f32_16x16x32_bf16(*kp, bb, acc[mt], 0, 0, 0);
        }

        if (it + 1 < J32) { yA = yAn; yB = yBn; bb = bbn; }
    }

    // Epilogue: D layout row=quad*4+s, col=n; JSPLIT partial sums via atomics
#pragma unroll
    for (int mt = 0; mt < MT; ++mt)
#pragma unroll
        for (int s = 0; s < 4; ++s) {
            const int row = waverow + mt * 16 + quad * 4 + s;
            atomicAdd(out + (size_t)row * DV + n, acc[mt][s]);
        }
}

extern "C" void kernel_launch(void* const* d_in, const int* in_sizes, int n_in,
                              void* d_out, int out_size, void* d_ws, size_t ws_size,
                              hipStream_t stream) {
    const float* ls = (const float*)d_in[0];
    const float* x  = (const float*)d_in[1];
    const float* y  = (const float*)d_in[2];
    const float* b  = (const float*)d_in[3];
    float* out = (float*)d_out;

    char* ws = (char*)d_ws;
    bf8* ytbl = (bf8*)ws;                        // 1024*64*16B = 1 MB
    bf8* btbl = (bf8*)(ws + (1 << 20));          // 512*64*16B  = 512 KB

    prep_frags<<<384, 256, 0, stream>>>(ls, y, b, ytbl, btbl, (float4*)out);
    matern_mfma<<<dim3(NN / ROWS_BLK, JSPLIT), 256, 0, stream>>>(ls, x, ytbl, btbl, out);
}